// Round 16
// baseline (10130.121 us; speedup 1.0000x reference)
//
#include <hip/hip_runtime.h>

#define Tq 256
#define Sq 512
#define Hq 512
#define H2q 1024
#define KPACK 1664   // trg(128) | outs(512) | ctx(1024)

typedef __attribute__((ext_vector_type(8))) short short8_t;
typedef __attribute__((ext_vector_type(4))) float f32x4;

__device__ __forceinline__ float bf2f(ushort u){ return __uint_as_float(((unsigned)u)<<16); }
__device__ __forceinline__ ushort f2bf(float f){
  unsigned u = __float_as_uint(f);
  u += 0x7FFFu + ((u>>16)&1u);
  return (ushort)(u>>16);
}
__device__ __forceinline__ float frcp(float x){ return __builtin_amdgcn_rcpf(x); }
__device__ __forceinline__ float fexp2(float x){ return __builtin_amdgcn_exp2f(x); }
// tanh(x) = 1 - 2/(e^{2x}+1);  e^{2x} = 2^{2*log2(e)*x}
__device__ __forceinline__ float ftanh(float x){
  return 1.f - 2.f*frcp(fexp2(2.8853900818f*x) + 1.f);
}
__device__ __forceinline__ float fsig(float x){
  return frcp(1.f + fexp2(-1.4426950409f*x));
}

// ---------------- guard bail (f32 out) ----------------
__global__ void bail_kernel(float* out, float v){
  if (threadIdx.x < 256) out[threadIdx.x] = v;
}

// ---------------- conversion kernels ----------------
__global__ void conv_bf16(const float* __restrict__ src, ushort* __restrict__ dst, int n4){
  int idx = blockIdx.x*blockDim.x + threadIdx.x;
  if (idx >= n4) return;
  float4 v = ((const float4*)src)[idx];
  ushort4 o; o.x = f2bf(v.x); o.y = f2bf(v.y); o.z = f2bf(v.z); o.w = f2bf(v.w);
  ((ushort4*)dst)[idx] = o;
}

__global__ void conv_fp8(const float* __restrict__ src, unsigned* __restrict__ dst, int n4){
  int idx = blockIdx.x*blockDim.x + threadIdx.x;
  if (idx >= n4) return;
  float4 v = ((const float4*)src)[idx];
  unsigned u = __builtin_amdgcn_cvt_pk_fp8_f32(v.x, v.y, 0u, false);
  u = __builtin_amdgcn_cvt_pk_fp8_f32(v.z, v.w, u, true);
  dst[idx] = u;
}

__global__ void pack_trg(const float* __restrict__ trg, ushort* __restrict__ packed, int n4){
  int idx = blockIdx.x*blockDim.x + threadIdx.x;
  if (idx >= n4) return;                 // n4 = B*T*E/4
  float4 v = ((const float4*)trg)[idx];
  int bt = idx >> 5, r = idx & 31;       // E/4 = 32
  ushort4 o; o.x = f2bf(v.x); o.y = f2bf(v.y); o.z = f2bf(v.z); o.w = f2bf(v.w);
  *(ushort4*)&packed[(long)bt*KPACK + r*4] = o;
}

__global__ void bsum_kernel(const float* __restrict__ a, const float* __restrict__ b,
                            float* __restrict__ o, int n){
  int idx = blockIdx.x*blockDim.x + threadIdx.x;
  if (idx < n) o[idx] = a[idx] + b[idx];
}

// vsum[0] = sum of all 512 v_att entries
__global__ void vsum_kernel(const float* __restrict__ v, float* __restrict__ o){
  __shared__ float red[8];
  int tid = threadIdx.x;
  float x = v[tid];
  #pragma unroll
  for (int off = 32; off; off >>= 1) x += __shfl_down(x, off);
  if ((tid & 63) == 0) red[tid >> 6] = x;
  __syncthreads();
  if (tid == 0) {
    float s = 0.f;
    #pragma unroll
    for (int i = 0; i < 8; ++i) s += red[i];
    o[0] = s;
  }
}

// ---------------- bridge ----------------
__global__ __launch_bounds__(512)
void bridge_kernel(const float* __restrict__ efh, const float* __restrict__ efc,
                   const float* __restrict__ bhw, const float* __restrict__ bhb,
                   const float* __restrict__ bcw, const float* __restrict__ bcb,
                   float* __restrict__ hb0, float* __restrict__ cws)
{
  int b = blockIdx.x, n = threadIdx.x;
  __shared__ __align__(16) float eh_l[1024];
  __shared__ __align__(16) float ec_l[1024];
  eh_l[n]       = efh[b*1024 + n];
  eh_l[n + 512] = efh[b*1024 + 512 + n];
  ec_l[n]       = efc[b*1024 + n];
  ec_l[n + 512] = efc[b*1024 + 512 + n];
  __syncthreads();
  const float4* wh = (const float4*)(bhw + (long)n*1024);
  const float4* wc = (const float4*)(bcw + (long)n*1024);
  float ah = bhb[n], ac = bcb[n];
  for (int i = 0; i < 256; ++i) {
    float4 w1 = wh[i]; float4 w2 = wc[i];
    const float* e1 = &eh_l[i*4]; const float* e2 = &ec_l[i*4];
    ah += w1.x*e1[0] + w1.y*e1[1] + w1.z*e1[2] + w1.w*e1[3];
    ac += w2.x*e2[0] + w2.y*e2[1] + w2.z*e2[2] + w2.w*e2[3];
  }
  hb0[b*512 + n] = ftanh(ah);
  cws[b*512 + n] = ftanh(ac);
}

// ---------------- MFMA BT-GEMM: C[m,n] = sum_k A[m,k]*Bt[n,k] ----------------
// outMode: 0 = f32, 1 = bf16, 2 = fp8(e4m3, scaled by oscale)
__global__ __launch_bounds__(256)
void gemm_bt(const ushort* __restrict__ A, int lda, long sA,
             const ushort* __restrict__ Bt, int ldb, long sB,
             void* __restrict__ Cout, int ldc, long sC, int K, int outMode,
             float oscale)
{
  __shared__ __align__(16) ushort Al[128][40];
  __shared__ __align__(16) ushort Bl[128][40];
  int bz = blockIdx.z;
  const ushort* Ab = A + (long)bz*sA;
  const ushort* Bb = Bt + (long)bz*sB;
  int m0 = blockIdx.x*128, n0 = blockIdx.y*128;
  int tid = threadIdx.x;
  int lane = tid & 63, w = tid >> 6;
  int wm = w >> 1, wn = w & 1;
  f32x4 acc[4][4] = {};
  int frow = lane & 15, fk = (lane >> 4)*8;
  for (int k0 = 0; k0 < K; k0 += 32) {
    #pragma unroll
    for (int p = 0; p < 2; ++p) {
      int task = tid + p*256;
      int row = task >> 2, c8 = (task & 3)*8;
      uint4 va = *(const uint4*)(Ab + (long)(m0+row)*lda + k0 + c8);
      uint4 vb = *(const uint4*)(Bb + (long)(n0+row)*ldb + k0 + c8);
      *(uint4*)&Al[row][c8] = va;
      *(uint4*)&Bl[row][c8] = vb;
    }
    __syncthreads();
    short8_t af[4], bfr[4];
    #pragma unroll
    for (int mi = 0; mi < 4; ++mi) af[mi]  = *(const short8_t*)&Al[wm*64 + mi*16 + frow][fk];
    #pragma unroll
    for (int ni = 0; ni < 4; ++ni) bfr[ni] = *(const short8_t*)&Bl[wn*64 + ni*16 + frow][fk];
    #pragma unroll
    for (int mi = 0; mi < 4; ++mi)
      #pragma unroll
      for (int ni = 0; ni < 4; ++ni)
        acc[mi][ni] = __builtin_amdgcn_mfma_f32_16x16x32_bf16(af[mi], bfr[ni], acc[mi][ni], 0, 0, 0);
    __syncthreads();
  }
  int rbase = (lane >> 4)*4;
  int col = lane & 15;
  #pragma unroll
  for (int mi = 0; mi < 4; ++mi)
    #pragma unroll
    for (int ni = 0; ni < 4; ++ni)
      #pragma unroll
      for (int i = 0; i < 4; ++i) {
        int gm = m0 + wm*64 + mi*16 + rbase + i;
        int gn = n0 + wn*64 + ni*16 + col;
        float vv = acc[mi][ni][i];
        long off = (long)bz*sC + (long)gm*ldc + gn;
        if (outMode == 1)      ((ushort*)Cout)[off] = f2bf(vv);
        else if (outMode == 2) ((unsigned char*)Cout)[off] =
              (unsigned char)(__builtin_amdgcn_cvt_pk_fp8_f32(vv*oscale, 0.f, 0, false) & 0xFF);
        else                   ((float*)Cout)[off] = vv;
      }
}

// ---------------- qstep (t=0 only): q[b][n] = sum_k h[b][k] * Wq[n,k] ----------------
__global__ __launch_bounds__(512)
void qstep(const ushort* __restrict__ Wq, const float* __restrict__ hr,
           float* __restrict__ qbuf)
{
  __shared__ __align__(16) float h_s[512];
  int b = blockIdx.x, tid = threadIdx.x;
  h_s[tid] = hr[b*Hq + tid];
  __syncthreads();
  const ushort* wrow = Wq + (long)tid*Hq;
  float qa = 0.f;
  #pragma unroll 4
  for (int k = 0; k < 512; k += 8) {
    uint4 w4 = *(const uint4*)(wrow + k);
    const ushort* wu = (const ushort*)&w4;
    #pragma unroll
    for (int e = 0; e < 8; ++e) qa += h_s[k+e]*bf2f(wu[e]);
  }
  qbuf[b*Hq + tid] = qa;
}

// ---------------- scoreA: q-sum + scores(fp8 pk, pre-scaled) + exp + ctx/denom partials ----
// pk8 stores 2.8854*pk; q scaled on load; tanh folded: p = sum(-2 v r), sc = vsum + p
// 512 blocks: (b, j8); 64 s per block; threads = 8 hq x 64 sl
__global__ __launch_bounds__(512)
void scoreA(const unsigned char* __restrict__ pk8,
            const unsigned char* __restrict__ eh8,
            const ushort* __restrict__ qpart,  // bf16 [b][32][512]
            const float* __restrict__ qbuf,    // used when useQbuf
            const float* __restrict__ vatt,
            const float* __restrict__ vsumb,
            float* __restrict__ ctxp,
            float* __restrict__ denp,
            int useQbuf)
{
  __shared__ __align__(16) float q_s[512];
  __shared__ __align__(16) float v2_s[512];
  __shared__ __align__(16) float sred[512];
  __shared__ __align__(16) float e_s[64];
  int tid = threadIdx.x, blk = blockIdx.x;
  int b = blk >> 3, j8 = blk & 7, s0 = j8*64;
  float qraw;
  if (useQbuf) {
    qraw = qbuf[b*Hq + tid];
  } else {
    const ushort* qp = qpart + (long)b*32*512 + tid;
    float qa = 0.f;
    #pragma unroll 8
    for (int c = 0; c < 32; ++c) qa += bf2f(qp[c*512]);
    qraw = qa;
  }
  q_s[tid] = 2.8853900818f*qraw;
  v2_s[tid] = -2.f*vatt[tid];
  __syncthreads();
  int sl = tid & 63, hq = tid >> 6;   // 8 h-groups of 64
  {
    const unsigned char* pr = pk8 + ((long)b*Sq + s0 + sl)*Hq + hq*64;
    float p = 0.f;
    #pragma unroll
    for (int i = 0; i < 4; ++i) {
      uint4 w4 = *(const uint4*)(pr + i*16);
      const unsigned* uw = (const unsigned*)&w4;
      #pragma unroll
      for (int m = 0; m < 4; ++m) {
        unsigned u = uw[m];
        int hb = hq*64 + i*16 + m*4;
        p += v2_s[hb+0]*frcp(fexp2(__builtin_amdgcn_cvt_f32_fp8(u,0) + q_s[hb+0]) + 1.f);
        p += v2_s[hb+1]*frcp(fexp2(__builtin_amdgcn_cvt_f32_fp8(u,1) + q_s[hb+1]) + 1.f);
        p += v2_s[hb+2]*frcp(fexp2(__builtin_amdgcn_cvt_f32_fp8(u,2) + q_s[hb+2]) + 1.f);
        p += v2_s[hb+3]*frcp(fexp2(__builtin_amdgcn_cvt_f32_fp8(u,3) + q_s[hb+3]) + 1.f);
      }
    }
    sred[hq*64 + sl] = p;
  }
  __syncthreads();
  if (tid < 64) {
    float sc = vsumb[0];
    #pragma unroll
    for (int g = 0; g < 8; ++g) sc += sred[g*64 + tid];
    float e = fexp2(1.4426950409f*sc);
    e_s[tid] = e;
    float r = e;
    #pragma unroll
    for (int off = 32; off; off >>= 1) r += __shfl_down(r, off);
    if (tid == 0) denp[b*8 + j8] = r;
  }
  __syncthreads();
  // unnormalized ctx partial over 64 s, thread owns k = 2*tid, 2*tid+1 (fp8 eh)
  {
    const unsigned char* ep = eh8 + ((long)b*Sq + s0)*H2q + tid*2;
    float a0 = 0.f, a1 = 0.f;
    #pragma unroll 4
    for (int s = 0; s < 64; ++s) {
      unsigned u = (unsigned)(*(const ushort*)(ep + (long)s*H2q));
      float es = e_s[s];
      a0 += es*__builtin_amdgcn_cvt_f32_fp8(u,0);
      a1 += es*__builtin_amdgcn_cvt_f32_fp8(u,1);
    }
    float* cp = ctxp + ((long)b*8 + j8)*1024 + tid*2;
    cp[0] = a0; cp[1] = a1;
  }
}

// ---------------- gatesB: ctx + gates GEMM (2-row reg-blocked, bf16 x) + LSTM + q-partials
// 256 blocks: (c_bg of 8 b, c_rc of 32 chunks = 16 rows/gate = 64 rows); 512 thr = 16 ks x 32 rt
__global__ __launch_bounds__(512)
void gatesB(int t, ushort* packed,
            const ushort* __restrict__ Wih, const ushort* __restrict__ Whh,
            const ushort* __restrict__ Wq,
            const float* __restrict__ bsum, const float* __restrict__ hr,
            float* __restrict__ hw, float* __restrict__ cws,
            const float* __restrict__ ctxp, const float* __restrict__ denp,
            ushort* __restrict__ qpart,
            float* __restrict__ outs)
{
  __shared__ __align__(16) ushort x_l[8*1672];     // bf16 x, padded stride
  __shared__ __align__(16) float  redc[8192];      // [b8][ks16][rowslot64]
  __shared__ __align__(16) float  g_lds[512];      // [b8][rowslot64]
  __shared__ __align__(16) float  rden[8];
  __shared__ __align__(16) float  hn_s[128];       // [b8][hd16]
  int tid = threadIdx.x, blk = blockIdx.x;
  int c_bg = blk >> 5, c_rc = blk & 31;

  if (tid < 8) {
    int gb = c_bg*8 + tid;
    float d = 0.f;
    #pragma unroll
    for (int j = 0; j < 8; ++j) d += denp[gb*8 + j];
    rden[tid] = frcp(d);
  }
  // trg region of x (direct bf16 copy)
  for (int task = tid; task < 128; task += 512) {
    int bb = task >> 4, c8 = task & 15;
    int gb = c_bg*8 + bb;
    uint4 vv = *(const uint4*)(packed + (long)(gb*Tq + t)*KPACK + c8*8);
    *(uint4*)&x_l[bb*1672 + c8*8] = vv;
  }
  // h region of x (f32 -> bf16)
  for (int task = tid; task < 4096; task += 512) {
    int bb = task >> 9, kk = task & 511;
    x_l[bb*1672 + 1152 + kk] = f2bf(hr[(c_bg*8 + bb)*Hq + kk]);
  }
  __syncthreads();   // rden ready
  // ctx region of x (normalize 8 partials -> bf16); persist bf16 ctx for pre-GEMM
  for (int task = tid; task < 8192; task += 512) {
    int bb = task >> 10, kk = task & 1023;
    int gb = c_bg*8 + bb;
    const float* cp = ctxp + (long)gb*8192 + kk;
    float cv = 0.f;
    #pragma unroll
    for (int j = 0; j < 8; ++j) cv += cp[j*1024];
    cv *= rden[bb];
    ushort cb = f2bf(cv);
    x_l[bb*1672 + 128 + kk] = cb;
    if (c_rc == 0) packed[(long)(gb*Tq + t)*KPACK + 640 + kk] = cb;
  }
  __syncthreads();   // x ready
  float acc0[8] = {}, acc1[8] = {};
  int rt = tid & 31, ks = tid >> 5;
  int rowslot0 = rt*2;                  // rowslot1 = rowslot0+1, same gate
  int rr0 = (rowslot0 >> 4)*512 + c_rc*16 + (rowslot0 & 15);   // rr1 = rr0+1
  for (int kt = 0; kt < 13; ++kt) {
    const ushort* w0 = (kt < 9) ? (Wih + (long)rr0*1152 + kt*128 + ks*8)
                                : (Whh + (long)rr0*512  + (kt-9)*128 + ks*8);
    const ushort* w1 = w0 + ((kt < 9) ? 1152 : 512);
    uint4 wa = *(const uint4*)w0;
    uint4 wb = *(const uint4*)w1;
    const ushort* wua = (const ushort*)&wa;
    const ushort* wub = (const ushort*)&wb;
    float wf0[8], wf1[8];
    #pragma unroll
    for (int e = 0; e < 8; ++e) { wf0[e] = bf2f(wua[e]); wf1[e] = bf2f(wub[e]); }
    int xbase = kt*128 + ks*8;
    #pragma unroll
    for (int bb = 0; bb < 8; ++bb) {
      uint4 uv = *(const uint4*)&x_l[bb*1672 + xbase];
      float x0 = __uint_as_float(uv.x << 16), x1 = __uint_as_float(uv.x & 0xFFFF0000u);
      float x2 = __uint_as_float(uv.y << 16), x3 = __uint_as_float(uv.y & 0xFFFF0000u);
      float x4 = __uint_as_float(uv.z << 16), x5 = __uint_as_float(uv.z & 0xFFFF0000u);
      float x6 = __uint_as_float(uv.w << 16), x7 = __uint_as_float(uv.w & 0xFFFF0000u);
      acc0[bb] += wf0[0]*x0 + wf0[1]*x1 + wf0[2]*x2 + wf0[3]*x3
                + wf0[4]*x4 + wf0[5]*x5 + wf0[6]*x6 + wf0[7]*x7;
      acc1[bb] += wf1[0]*x0 + wf1[1]*x1 + wf1[2]*x2 + wf1[3]*x3
                + wf1[4]*x4 + wf1[5]*x5 + wf1[6]*x6 + wf1[7]*x7;
    }
  }
  __syncthreads();
  #pragma unroll
  for (int bb = 0; bb < 8; ++bb) {
    redc[bb*1024 + ks*64 + rowslot0]     = acc0[bb];
    redc[bb*1024 + ks*64 + rowslot0 + 1] = acc1[bb];
  }
  __syncthreads();
  {
    int rowslot = tid & 63, bb = tid >> 6;
    float gvv = bsum[(rowslot >> 4)*512 + c_rc*16 + (rowslot & 15)];
    #pragma unroll
    for (int q2 = 0; q2 < 16; ++q2) gvv += redc[bb*1024 + q2*64 + rowslot];
    g_lds[bb*64 + rowslot] = gvv;
  }
  __syncthreads();
  if (tid < 128) {
    int bb = tid >> 4, i2 = tid & 15;
    int gb = c_bg*8 + bb;
    int hd = c_rc*16 + i2;
    float gi = g_lds[bb*64 +  0 + i2];
    float gf = g_lds[bb*64 + 16 + i2];
    float gg = g_lds[bb*64 + 32 + i2];
    float go = g_lds[bb*64 + 48 + i2];
    float co = cws[gb*Hq + hd];
    float cn = fsig(gf)*co + fsig(gi)*ftanh(gg);
    float hn = fsig(go)*ftanh(cn);
    cws[gb*Hq + hd] = cn;
    hw[gb*Hq + hd] = hn;
    outs[(long)(gb*Tq + t)*Hq + hd] = hn;
    packed[(long)(gb*Tq + t)*KPACK + 128 + hd] = f2bf(hn);
    hn_s[bb*16 + i2] = hn;
  }
  __syncthreads();
  // q-partials (bf16) for step t+1: qpart[gb][c_rc][n=tid] = sum_{i2<16} hn*Wq[n][c_rc*16+i2]
  {
    const ushort* wr = Wq + (long)tid*Hq + c_rc*16;
    uint4 wa = *(const uint4*)wr;
    uint4 wb = *(const uint4*)(wr + 8);
    const ushort* wua = (const ushort*)&wa;
    const ushort* wub = (const ushort*)&wb;
    float wf[16];
    #pragma unroll
    for (int e = 0; e < 8; ++e) { wf[e] = bf2f(wua[e]); wf[8+e] = bf2f(wub[e]); }
    #pragma unroll
    for (int bb = 0; bb < 8; ++bb) {
      const float* hp = &hn_s[bb*16];
      float qa = 0.f;
      #pragma unroll
      for (int e = 0; e < 16; ++e) qa += wf[e]*hp[e];
      qpart[((long)(c_bg*8 + bb)*32 + c_rc)*512 + tid] = f2bf(qa);
    }
  }
}

__global__ void epilogue_copy(const float* __restrict__ hb0, const float* __restrict__ cws,
                              float* __restrict__ dout){
  int idx = blockIdx.x*blockDim.x + threadIdx.x;
  if (idx < 32768) {
    dout[8388608 + idx] = hb0[idx];
    dout[8421376 + idx] = cws[idx];
  }
}

extern "C" void kernel_launch(void* const* d_in, const int* in_sizes, int n_in,
                              void* d_out, int out_size, void* d_ws, size_t ws_size,
                              hipStream_t stream)
{
  float* out = (float*)d_out;
  static const int expect[18] = {2097152,33554432,65536,65536,32768,16384,
                                 524288,262144,512,524288,512,524288,512,
                                 2359296,1048576,2048,2048,851968};
  if (n_in != 18 || out_size != 16842752) {
    bail_kernel<<<1, 256, 0, stream>>>(out, 33.0f); return;
  }
  for (int i = 0; i < 18; ++i) if (in_sizes[i] != expect[i]) {
    bail_kernel<<<1, 256, 0, stream>>>(out, 100.0f + i); return;
  }
  if (ws_size < 166207552ULL) { bail_kernel<<<1, 256, 0, stream>>>(out, 77.0f); return; }

  const float* trg  = (const float*)d_in[0];
  const float* eh   = (const float*)d_in[1];
  const float* efh  = (const float*)d_in[2];
  const float* efc  = (const float*)d_in[3];
  const float* Wk   = (const float*)d_in[6];
  const float* Wq   = (const float*)d_in[7];
  const float* v    = (const float*)d_in[8];
  const float* bhw  = (const float*)d_in[9];
  const float* bhb  = (const float*)d_in[10];
  const float* bcw  = (const float*)d_in[11];
  const float* bcb  = (const float*)d_in[12];
  const float* Wih  = (const float*)d_in[13];
  const float* Whh  = (const float*)d_in[14];
  const float* bih  = (const float*)d_in[15];
  const float* bhh  = (const float*)d_in[16];
  const float* Wpre = (const float*)d_in[17];
  char* ws = (char*)d_ws;

  ushort* ehb          = (ushort*)(ws + 0);        // bf16 eh (prologue only)
  unsigned char* eh8   = (unsigned char*)(ws + 0); // fp8 eh overlays ehb after pk8 GEMM
  unsigned char* pk8   = (unsigned char*)(ws + 67108864);
  ushort* packed       = (ushort*)(ws + 83886080);
  ushort* Wk_b         = (ushort*)(ws + 138412032);
  ushort* Wq_b         = (ushort*)(ws + 139460608);
  ushort* Wih_b        = (ushort*)(ws + 139984896);
  ushort* Whh_b        = (ushort*)(ws + 144703488);
  ushort* Wpre_b       = (ushort*)(ws + 146800640);
  float*  qbuf         = (float*)(ws + 148504576);
  float*  ctxp         = (float*)(ws + 148635648);
  float*  denp         = (float*)(ws + 150732800);
  float*  bsum         = (float*)(ws + 150734848);
  float*  hb0          = (float*)(ws + 150743040);
  float*  hb1          = (float*)(ws + 150874112);
  float*  cws          = (float*)(ws + 151005184);
  ushort* qpart        = (ushort*)(ws + 151136256);  // bf16 64*32*512*2 = 2 MB
  float*  vsumb        = (float*)(ws + 153233408);

  auto cb = [&](const float* s, ushort* d, int n){
    int n4 = n/4;
    conv_bf16<<<(n4 + 255)/256, 256, 0, stream>>>(s, d, n4);
  };
  cb(eh,   ehb,   64*512*1024);
  cb(Wk,   Wk_b,  512*1024);
  cb(Wq,   Wq_b,  512*512);
  cb(Wih,  Wih_b, 2048*1152);
  cb(Whh,  Whh_b, 2048*512);
  cb(Wpre, Wpre_b,512*1664);
  pack_trg<<<(524288 + 255)/256, 256, 0, stream>>>(trg, packed, 524288);
  bsum_kernel<<<8, 256, 0, stream>>>(bih, bhh, bsum, 2048);
  vsum_kernel<<<1, 512, 0, stream>>>(v, vsumb);
  bridge_kernel<<<64, 512, 0, stream>>>(efh, efc, bhw, bhb, bcw, bcb, hb0, cws);
  // pk8[b][s][h] = 2.8854 * sum_k eh[b,s,k]*Wk[h,k]  (fp8 e4m3, pre-scaled for exp2 fold)
  gemm_bt<<<dim3(4,4,64), 256, 0, stream>>>(ehb, 1024, 524288L, Wk_b, 1024, 0L,
                                            (void*)pk8, 512, 262144L, 1024, 2, 2.8853900818f);
  // eh -> fp8 overlay (ehb no longer needed)
  conv_fp8<<<(8388608 + 255)/256, 256, 0, stream>>>(eh, (unsigned*)eh8, 8388608);
  qstep<<<64, 512, 0, stream>>>(Wq_b, hb0, qbuf);

  for (int t = 0; t < 256; ++t) {
    const float* hr = (t & 1) ? hb1 : hb0;
    float*       hw = (t & 1) ? hb0 : hb1;
    scoreA<<<512, 512, 0, stream>>>(pk8, eh8, qpart, qbuf, v, vsumb, ctxp, denp,
                                    (t == 0) ? 1 : 0);
    gatesB<<<256, 512, 0, stream>>>(t, packed, Wih_b, Whh_b, Wq_b, bsum, hr, hw, cws,
                                    ctxp, denp, qpart, out);
  }

  epilogue_copy<<<128, 256, 0, stream>>>(hb0, cws, out);
  // pre[(b,t)][n] = sum_k packed[(b,t),k] * Wpre[n,k]  -> f32 output
  gemm_bt<<<dim3(128,4,1), 256, 0, stream>>>(packed, 1664, 0L, Wpre_b, 1664, 0L,
                                             (void*)(out + 8454144), 512, 0L, 1664, 0, 1.f);
}

// Round 17
// 9115.107 us; speedup vs baseline: 1.1114x; 1.1114x over previous
//
#include <hip/hip_runtime.h>

#define Tq 256
#define Sq 512
#define Hq 512
#define H2q 1024
#define KPACK 1664   // trg(128) | outs(512) | ctx(1024)

typedef __attribute__((ext_vector_type(8))) short short8_t;
typedef __attribute__((ext_vector_type(4))) float f32x4;

__device__ __forceinline__ float bf2f(ushort u){ return __uint_as_float(((unsigned)u)<<16); }
__device__ __forceinline__ ushort f2bf(float f){
  unsigned u = __float_as_uint(f);
  u += 0x7FFFu + ((u>>16)&1u);
  return (ushort)(u>>16);
}
__device__ __forceinline__ float frcp(float x){ return __builtin_amdgcn_rcpf(x); }
__device__ __forceinline__ float fexp2(float x){ return __builtin_amdgcn_exp2f(x); }
// tanh(x) = 1 - 2/(e^{2x}+1);  e^{2x} = 2^{2*log2(e)*x}
__device__ __forceinline__ float ftanh(float x){
  return 1.f - 2.f*frcp(fexp2(2.8853900818f*x) + 1.f);
}
__device__ __forceinline__ float fsig(float x){
  return frcp(1.f + fexp2(-1.4426950409f*x));
}

// ---------------- guard bail (f32 out) ----------------
__global__ void bail_kernel(float* out, float v){
  if (threadIdx.x < 256) out[threadIdx.x] = v;
}

// ---------------- conversion kernels ----------------
__global__ void conv_bf16(const float* __restrict__ src, ushort* __restrict__ dst, int n4){
  int idx = blockIdx.x*blockDim.x + threadIdx.x;
  if (idx >= n4) return;
  float4 v = ((const float4*)src)[idx];
  ushort4 o; o.x = f2bf(v.x); o.y = f2bf(v.y); o.z = f2bf(v.z); o.w = f2bf(v.w);
  ((ushort4*)dst)[idx] = o;
}

__global__ void conv_fp8(const float* __restrict__ src, unsigned* __restrict__ dst, int n4){
  int idx = blockIdx.x*blockDim.x + threadIdx.x;
  if (idx >= n4) return;
  float4 v = ((const float4*)src)[idx];
  unsigned u = __builtin_amdgcn_cvt_pk_fp8_f32(v.x, v.y, 0u, false);
  u = __builtin_amdgcn_cvt_pk_fp8_f32(v.z, v.w, u, true);
  dst[idx] = u;
}

__global__ void pack_trg(const float* __restrict__ trg, ushort* __restrict__ packed, int n4){
  int idx = blockIdx.x*blockDim.x + threadIdx.x;
  if (idx >= n4) return;                 // n4 = B*T*E/4
  float4 v = ((const float4*)trg)[idx];
  int bt = idx >> 5, r = idx & 31;       // E/4 = 32
  ushort4 o; o.x = f2bf(v.x); o.y = f2bf(v.y); o.z = f2bf(v.z); o.w = f2bf(v.w);
  *(ushort4*)&packed[(long)bt*KPACK + r*4] = o;
}

__global__ void bsum_kernel(const float* __restrict__ a, const float* __restrict__ b,
                            float* __restrict__ o, int n){
  int idx = blockIdx.x*blockDim.x + threadIdx.x;
  if (idx < n) o[idx] = a[idx] + b[idx];
}

// ---------------- bridge ----------------
__global__ __launch_bounds__(512)
void bridge_kernel(const float* __restrict__ efh, const float* __restrict__ efc,
                   const float* __restrict__ bhw, const float* __restrict__ bhb,
                   const float* __restrict__ bcw, const float* __restrict__ bcb,
                   float* __restrict__ hb0, float* __restrict__ cws)
{
  int b = blockIdx.x, n = threadIdx.x;
  __shared__ __align__(16) float eh_l[1024];
  __shared__ __align__(16) float ec_l[1024];
  eh_l[n]       = efh[b*1024 + n];
  eh_l[n + 512] = efh[b*1024 + 512 + n];
  ec_l[n]       = efc[b*1024 + n];
  ec_l[n + 512] = efc[b*1024 + 512 + n];
  __syncthreads();
  const float4* wh = (const float4*)(bhw + (long)n*1024);
  const float4* wc = (const float4*)(bcw + (long)n*1024);
  float ah = bhb[n], ac = bcb[n];
  for (int i = 0; i < 256; ++i) {
    float4 w1 = wh[i]; float4 w2 = wc[i];
    const float* e1 = &eh_l[i*4]; const float* e2 = &ec_l[i*4];
    ah += w1.x*e1[0] + w1.y*e1[1] + w1.z*e1[2] + w1.w*e1[3];
    ac += w2.x*e2[0] + w2.y*e2[1] + w2.z*e2[2] + w2.w*e2[3];
  }
  hb0[b*512 + n] = ftanh(ah);
  cws[b*512 + n] = ftanh(ac);
}

// ---------------- MFMA BT-GEMM: C[m,n] = sum_k A[m,k]*Bt[n,k] ----------------
// outMode: 0 = f32, 1 = bf16, 2 = fp8(e4m3)
__global__ __launch_bounds__(256)
void gemm_bt(const ushort* __restrict__ A, int lda, long sA,
             const ushort* __restrict__ Bt, int ldb, long sB,
             void* __restrict__ Cout, int ldc, long sC, int K, int outMode)
{
  __shared__ __align__(16) ushort Al[128][40];
  __shared__ __align__(16) ushort Bl[128][40];
  int bz = blockIdx.z;
  const ushort* Ab = A + (long)bz*sA;
  const ushort* Bb = Bt + (long)bz*sB;
  int m0 = blockIdx.x*128, n0 = blockIdx.y*128;
  int tid = threadIdx.x;
  int lane = tid & 63, w = tid >> 6;
  int wm = w >> 1, wn = w & 1;
  f32x4 acc[4][4] = {};
  int frow = lane & 15, fk = (lane >> 4)*8;
  for (int k0 = 0; k0 < K; k0 += 32) {
    #pragma unroll
    for (int p = 0; p < 2; ++p) {
      int task = tid + p*256;
      int row = task >> 2, c8 = (task & 3)*8;
      uint4 va = *(const uint4*)(Ab + (long)(m0+row)*lda + k0 + c8);
      uint4 vb = *(const uint4*)(Bb + (long)(n0+row)*ldb + k0 + c8);
      *(uint4*)&Al[row][c8] = va;
      *(uint4*)&Bl[row][c8] = vb;
    }
    __syncthreads();
    short8_t af[4], bfr[4];
    #pragma unroll
    for (int mi = 0; mi < 4; ++mi) af[mi]  = *(const short8_t*)&Al[wm*64 + mi*16 + frow][fk];
    #pragma unroll
    for (int ni = 0; ni < 4; ++ni) bfr[ni] = *(const short8_t*)&Bl[wn*64 + ni*16 + frow][fk];
    #pragma unroll
    for (int mi = 0; mi < 4; ++mi)
      #pragma unroll
      for (int ni = 0; ni < 4; ++ni)
        acc[mi][ni] = __builtin_amdgcn_mfma_f32_16x16x32_bf16(af[mi], bfr[ni], acc[mi][ni], 0, 0, 0);
    __syncthreads();
  }
  int rbase = (lane >> 4)*4;
  int col = lane & 15;
  #pragma unroll
  for (int mi = 0; mi < 4; ++mi)
    #pragma unroll
    for (int ni = 0; ni < 4; ++ni)
      #pragma unroll
      for (int i = 0; i < 4; ++i) {
        int gm = m0 + wm*64 + mi*16 + rbase + i;
        int gn = n0 + wn*64 + ni*16 + col;
        float vv = acc[mi][ni][i];
        long off = (long)bz*sC + (long)gm*ldc + gn;
        if (outMode == 1)      ((ushort*)Cout)[off] = f2bf(vv);
        else if (outMode == 2) ((unsigned char*)Cout)[off] =
              (unsigned char)(__builtin_amdgcn_cvt_pk_fp8_f32(vv, 0.f, 0, false) & 0xFF);
        else                   ((float*)Cout)[off] = vv;
      }
}

// ---------------- qstep (t=0 only): q[b][n] = sum_k h[b][k] * Wq[n,k] ----------------
__global__ __launch_bounds__(512)
void qstep(const ushort* __restrict__ Wq, const float* __restrict__ hr,
           float* __restrict__ qbuf)
{
  __shared__ __align__(16) float h_s[512];
  int b = blockIdx.x, tid = threadIdx.x;
  h_s[tid] = hr[b*Hq + tid];
  __syncthreads();
  const ushort* wrow = Wq + (long)tid*Hq;
  float qa = 0.f;
  #pragma unroll 4
  for (int k = 0; k < 512; k += 8) {
    uint4 w4 = *(const uint4*)(wrow + k);
    const ushort* wu = (const ushort*)&w4;
    #pragma unroll
    for (int e = 0; e < 8; ++e) qa += h_s[k+e]*bf2f(wu[e]);
  }
  qbuf[b*Hq + tid] = qa;
}

// ---------------- scoreA: q-sum + scores(fp8 pk) + exp + ctx(fp8 eh)/denom partials ----
// 512 blocks: (b, j8); 64 s per block; threads = 8 hq x 64 sl
__global__ __launch_bounds__(512)
void scoreA(const unsigned char* __restrict__ pk8,
            const unsigned char* __restrict__ eh8,
            const ushort* __restrict__ qpart,  // bf16 [b][32][512]
            const float* __restrict__ qbuf,    // used when useQbuf
            const float* __restrict__ vatt,
            float* __restrict__ ctxp,
            float* __restrict__ denp,
            int useQbuf)
{
  __shared__ __align__(16) float q_s[512];
  __shared__ __align__(16) float v_s[512];
  __shared__ __align__(16) float sred[512];
  __shared__ __align__(16) float e_s[64];
  int tid = threadIdx.x, blk = blockIdx.x;
  int b = blk >> 3, j8 = blk & 7, s0 = j8*64;
  if (useQbuf) {
    q_s[tid] = qbuf[b*Hq + tid];
  } else {
    const ushort* qp = qpart + (long)b*32*512 + tid;
    float qa = 0.f;
    #pragma unroll 8
    for (int c = 0; c < 32; ++c) qa += bf2f(qp[c*512]);
    q_s[tid] = qa;
  }
  v_s[tid] = vatt[tid];
  __syncthreads();
  int sl = tid & 63, hq = tid >> 6;   // 8 h-groups of 64
  {
    const unsigned char* pr = pk8 + ((long)b*Sq + s0 + sl)*Hq + hq*64;
    float p = 0.f;
    #pragma unroll
    for (int i = 0; i < 4; ++i) {
      uint4 w4 = *(const uint4*)(pr + i*16);
      const unsigned* uw = (const unsigned*)&w4;
      #pragma unroll
      for (int m = 0; m < 4; ++m) {
        unsigned u = uw[m];
        int hb = hq*64 + i*16 + m*4;
        p += v_s[hb+0]*ftanh(__builtin_amdgcn_cvt_f32_fp8(u,0) + q_s[hb+0]);
        p += v_s[hb+1]*ftanh(__builtin_amdgcn_cvt_f32_fp8(u,1) + q_s[hb+1]);
        p += v_s[hb+2]*ftanh(__builtin_amdgcn_cvt_f32_fp8(u,2) + q_s[hb+2]);
        p += v_s[hb+3]*ftanh(__builtin_amdgcn_cvt_f32_fp8(u,3) + q_s[hb+3]);
      }
    }
    sred[hq*64 + sl] = p;
  }
  __syncthreads();
  if (tid < 64) {
    float sc = 0.f;
    #pragma unroll
    for (int g = 0; g < 8; ++g) sc += sred[g*64 + tid];
    float e = fexp2(1.4426950409f*sc);
    e_s[tid] = e;
    float r = e;
    #pragma unroll
    for (int off = 32; off; off >>= 1) r += __shfl_down(r, off);
    if (tid == 0) denp[b*8 + j8] = r;
  }
  __syncthreads();
  // unnormalized ctx partial over 64 s, thread owns k = 2*tid, 2*tid+1 (fp8 eh)
  {
    const unsigned char* ep = eh8 + ((long)b*Sq + s0)*H2q + tid*2;
    float a0 = 0.f, a1 = 0.f;
    #pragma unroll 4
    for (int s = 0; s < 64; ++s) {
      unsigned u = (unsigned)(*(const ushort*)(ep + (long)s*H2q));
      float es = e_s[s];
      a0 += es*__builtin_amdgcn_cvt_f32_fp8(u,0);
      a1 += es*__builtin_amdgcn_cvt_f32_fp8(u,1);
    }
    float* cp = ctxp + ((long)b*8 + j8)*1024 + tid*2;
    cp[0] = a0; cp[1] = a1;
  }
}

// ---------------- gatesB: ctx + gates GEMM (2-row reg-blocked) + LSTM + q-partials ----
// 256 blocks: (c_bg of 8 b, c_rc of 32 chunks = 16 rows/gate = 64 rows); 512 thr = 16 ks x 32 rt
__global__ __launch_bounds__(512)
void gatesB(int t, ushort* packed,
            const ushort* __restrict__ Wih, const ushort* __restrict__ Whh,
            const ushort* __restrict__ Wq,
            const float* __restrict__ bsum, const float* __restrict__ hr,
            float* __restrict__ hw, float* __restrict__ cws,
            const float* __restrict__ ctxp, const float* __restrict__ denp,
            ushort* __restrict__ qpart,
            float* __restrict__ outs)
{
  __shared__ __align__(16) float x_lds[8*KPACK];   // 53 KB; aliased as redc after FMA
  __shared__ __align__(16) float g_lds[512];       // 8 bb x 64 rowslot
  __shared__ __align__(16) float rden[8];
  __shared__ __align__(16) float hn_s[128];        // 8 bb x 16 hd
  float* redc = x_lds;                             // 8192 f32 needed, fits
  int tid = threadIdx.x, blk = blockIdx.x;
  int c_bg = blk >> 5, c_rc = blk & 31;

  if (tid < 8) {
    int gb = c_bg*8 + tid;
    float d = 0.f;
    #pragma unroll
    for (int j = 0; j < 8; ++j) d += denp[gb*8 + j];
    rden[tid] = frcp(d);
  }
  // trg region of x
  for (int task = tid; task < 128; task += 512) {
    int bb = task >> 4, c8 = task & 15;
    int gb = c_bg*8 + bb;
    uint4 vv = *(const uint4*)(packed + (long)(gb*Tq + t)*KPACK + c8*8);
    const ushort* uu = (const ushort*)&vv;
    #pragma unroll
    for (int e = 0; e < 8; ++e) x_lds[bb*KPACK + c8*8 + e] = bf2f(uu[e]);
  }
  // h region of x
  for (int task = tid; task < 4096; task += 512) {
    int bb = task >> 9, kk = task & 511;
    x_lds[bb*KPACK + 1152 + kk] = hr[(c_bg*8 + bb)*Hq + kk];
  }
  __syncthreads();   // rden ready
  // ctx region of x (normalize 8 partials); persist bf16 ctx for pre-GEMM
  for (int task = tid; task < 8192; task += 512) {
    int bb = task >> 10, kk = task & 1023;
    int gb = c_bg*8 + bb;
    const float* cp = ctxp + (long)gb*8192 + kk;
    float cv = 0.f;
    #pragma unroll
    for (int j = 0; j < 8; ++j) cv += cp[j*1024];
    cv *= rden[bb];
    x_lds[bb*KPACK + 128 + kk] = cv;
    if (c_rc == 0) packed[(long)(gb*Tq + t)*KPACK + 640 + kk] = f2bf(cv);
  }
  __syncthreads();   // x ready
  float acc0[8] = {}, acc1[8] = {};
  int rt = tid & 31, ks = tid >> 5;
  int rowslot0 = rt*2;                  // rowslot1 = rowslot0+1, same gate
  int rr0 = (rowslot0 >> 4)*512 + c_rc*16 + (rowslot0 & 15);   // rr1 = rr0+1
  for (int kt = 0; kt < 13; ++kt) {
    const ushort* w0 = (kt < 9) ? (Wih + (long)rr0*1152 + kt*128 + ks*8)
                                : (Whh + (long)rr0*512  + (kt-9)*128 + ks*8);
    const ushort* w1 = w0 + ((kt < 9) ? 1152 : 512);
    uint4 wa = *(const uint4*)w0;
    uint4 wb = *(const uint4*)w1;
    const ushort* wua = (const ushort*)&wa;
    const ushort* wub = (const ushort*)&wb;
    float wf0[8], wf1[8];
    #pragma unroll
    for (int e = 0; e < 8; ++e) { wf0[e] = bf2f(wua[e]); wf1[e] = bf2f(wub[e]); }
    int xbase = kt*128 + ks*8;
    #pragma unroll
    for (int bb = 0; bb < 8; ++bb) {
      const float* xp = &x_lds[bb*KPACK + xbase];
      float4 x0 = *(const float4*)xp;
      float4 x1 = *(const float4*)(xp + 4);
      acc0[bb] += wf0[0]*x0.x + wf0[1]*x0.y + wf0[2]*x0.z + wf0[3]*x0.w
                + wf0[4]*x1.x + wf0[5]*x1.y + wf0[6]*x1.z + wf0[7]*x1.w;
      acc1[bb] += wf1[0]*x0.x + wf1[1]*x0.y + wf1[2]*x0.z + wf1[3]*x0.w
                + wf1[4]*x1.x + wf1[5]*x1.y + wf1[6]*x1.z + wf1[7]*x1.w;
    }
  }
  __syncthreads();   // all x reads done; redc aliases x_lds
  #pragma unroll
  for (int bb = 0; bb < 8; ++bb) {
    redc[bb*1024 + ks*64 + rowslot0]     = acc0[bb];
    redc[bb*1024 + ks*64 + rowslot0 + 1] = acc1[bb];
  }
  __syncthreads();
  {
    int rowslot = tid & 63, bb = tid >> 6;
    float gvv = bsum[(rowslot >> 4)*512 + c_rc*16 + (rowslot & 15)];
    #pragma unroll
    for (int q2 = 0; q2 < 16; ++q2) gvv += redc[bb*1024 + q2*64 + rowslot];
    g_lds[bb*64 + rowslot] = gvv;
  }
  __syncthreads();
  if (tid < 128) {
    int bb = tid >> 4, i2 = tid & 15;
    int gb = c_bg*8 + bb;
    int hd = c_rc*16 + i2;
    float gi = g_lds[bb*64 +  0 + i2];
    float gf = g_lds[bb*64 + 16 + i2];
    float gg = g_lds[bb*64 + 32 + i2];
    float go = g_lds[bb*64 + 48 + i2];
    float co = cws[gb*Hq + hd];
    float cn = fsig(gf)*co + fsig(gi)*ftanh(gg);
    float hn = fsig(go)*ftanh(cn);
    cws[gb*Hq + hd] = cn;
    hw[gb*Hq + hd] = hn;
    outs[(long)(gb*Tq + t)*Hq + hd] = hn;
    packed[(long)(gb*Tq + t)*KPACK + 128 + hd] = f2bf(hn);
    hn_s[bb*16 + i2] = hn;
  }
  __syncthreads();
  // q-partials (bf16) for step t+1: qpart[gb][c_rc][n=tid] = sum_{i2<16} hn*Wq[n][c_rc*16+i2]
  {
    const ushort* wr = Wq + (long)tid*Hq + c_rc*16;
    uint4 wa = *(const uint4*)wr;
    uint4 wb = *(const uint4*)(wr + 8);
    const ushort* wua = (const ushort*)&wa;
    const ushort* wub = (const ushort*)&wb;
    float wf[16];
    #pragma unroll
    for (int e = 0; e < 8; ++e) { wf[e] = bf2f(wua[e]); wf[8+e] = bf2f(wub[e]); }
    #pragma unroll
    for (int bb = 0; bb < 8; ++bb) {
      const float* hp = &hn_s[bb*16];
      float qa = 0.f;
      #pragma unroll
      for (int e = 0; e < 16; ++e) qa += wf[e]*hp[e];
      qpart[((long)(c_bg*8 + bb)*32 + c_rc)*512 + tid] = f2bf(qa);
    }
  }
}

__global__ void epilogue_copy(const float* __restrict__ hb0, const float* __restrict__ cws,
                              float* __restrict__ dout){
  int idx = blockIdx.x*blockDim.x + threadIdx.x;
  if (idx < 32768) {
    dout[8388608 + idx] = hb0[idx];
    dout[8421376 + idx] = cws[idx];
  }
}

extern "C" void kernel_launch(void* const* d_in, const int* in_sizes, int n_in,
                              void* d_out, int out_size, void* d_ws, size_t ws_size,
                              hipStream_t stream)
{
  float* out = (float*)d_out;
  static const int expect[18] = {2097152,33554432,65536,65536,32768,16384,
                                 524288,262144,512,524288,512,524288,512,
                                 2359296,1048576,2048,2048,851968};
  if (n_in != 18 || out_size != 16842752) {
    bail_kernel<<<1, 256, 0, stream>>>(out, 33.0f); return;
  }
  for (int i = 0; i < 18; ++i) if (in_sizes[i] != expect[i]) {
    bail_kernel<<<1, 256, 0, stream>>>(out, 100.0f + i); return;
  }
  if (ws_size < 166207552ULL) { bail_kernel<<<1, 256, 0, stream>>>(out, 77.0f); return; }

  const float* trg  = (const float*)d_in[0];
  const float* eh   = (const float*)d_in[1];
  const float* efh  = (const float*)d_in[2];
  const float* efc  = (const float*)d_in[3];
  const float* Wk   = (const float*)d_in[6];
  const float* Wq   = (const float*)d_in[7];
  const float* v    = (const float*)d_in[8];
  const float* bhw  = (const float*)d_in[9];
  const float* bhb  = (const float*)d_in[10];
  const float* bcw  = (const float*)d_in[11];
  const float* bcb  = (const float*)d_in[12];
  const float* Wih  = (const float*)d_in[13];
  const float* Whh  = (const float*)d_in[14];
  const float* bih  = (const float*)d_in[15];
  const float* bhh  = (const float*)d_in[16];
  const float* Wpre = (const float*)d_in[17];
  char* ws = (char*)d_ws;

  ushort* ehb          = (ushort*)(ws + 0);        // bf16 eh (prologue only)
  unsigned char* eh8   = (unsigned char*)(ws + 0); // fp8 eh overlays ehb after pk8 GEMM
  unsigned char* pk8   = (unsigned char*)(ws + 67108864);
  ushort* packed       = (ushort*)(ws + 83886080);
  ushort* Wk_b         = (ushort*)(ws + 138412032);
  ushort* Wq_b         = (ushort*)(ws + 139460608);
  ushort* Wih_b        = (ushort*)(ws + 139984896);
  ushort* Whh_b        = (ushort*)(ws + 144703488);
  ushort* Wpre_b       = (ushort*)(ws + 146800640);
  float*  qbuf         = (float*)(ws + 148504576);
  float*  ctxp         = (float*)(ws + 148635648);
  float*  denp         = (float*)(ws + 150732800);
  float*  bsum         = (float*)(ws + 150734848);
  float*  hb0          = (float*)(ws + 150743040);
  float*  hb1          = (float*)(ws + 150874112);
  float*  cws          = (float*)(ws + 151005184);
  ushort* qpart        = (ushort*)(ws + 151136256);  // bf16 64*32*512*2 = 2 MB

  auto cb = [&](const float* s, ushort* d, int n){
    int n4 = n/4;
    conv_bf16<<<(n4 + 255)/256, 256, 0, stream>>>(s, d, n4);
  };
  cb(eh,   ehb,   64*512*1024);
  cb(Wk,   Wk_b,  512*1024);
  cb(Wq,   Wq_b,  512*512);
  cb(Wih,  Wih_b, 2048*1152);
  cb(Whh,  Whh_b, 2048*512);
  cb(Wpre, Wpre_b,512*1664);
  pack_trg<<<(524288 + 255)/256, 256, 0, stream>>>(trg, packed, 524288);
  bsum_kernel<<<8, 256, 0, stream>>>(bih, bhh, bsum, 2048);
  bridge_kernel<<<64, 512, 0, stream>>>(efh, efc, bhw, bhb, bcw, bcb, hb0, cws);
  // pk8[b][s][h] = sum_k eh[b,s,k]*Wk[h,k]  (fp8 e4m3 output)
  gemm_bt<<<dim3(4,4,64), 256, 0, stream>>>(ehb, 1024, 524288L, Wk_b, 1024, 0L,
                                            (void*)pk8, 512, 262144L, 1024, 2);
  // eh -> fp8 overlay (ehb no longer needed)
  conv_fp8<<<(8388608 + 255)/256, 256, 0, stream>>>(eh, (unsigned*)eh8, 8388608);
  qstep<<<64, 512, 0, stream>>>(Wq_b, hb0, qbuf);

  for (int t = 0; t < 256; ++t) {
    const float* hr = (t & 1) ? hb1 : hb0;
    float*       hw = (t & 1) ? hb0 : hb1;
    scoreA<<<512, 512, 0, stream>>>(pk8, eh8, qpart, qbuf, v, ctxp, denp, (t == 0) ? 1 : 0);
    gatesB<<<256, 512, 0, stream>>>(t, packed, Wih_b, Whh_b, Wq_b, bsum, hr, hw, cws,
                                    ctxp, denp, qpart, out);
  }

  epilogue_copy<<<128, 256, 0, stream>>>(hb0, cws, out);
  // pre[(b,t)][n] = sum_k packed[(b,t),k] * Wpre[n,k]  -> f32 output
  gemm_bt<<<dim3(128,4,1), 256, 0, stream>>>(packed, 1664, 0L, Wpre_b, 1664, 0L,
                                             (void*)(out + 8454144), 512, 0L, 1664, 0);
}